// Round 8
// baseline (327.671 us; speedup 1.0000x reference)
//
#include <hip/hip_runtime.h>
#include <hip/hip_bf16.h>

#define LRELU(val) ((val) >= 0.0f ? (val) : 0.01f * (val))

__device__ __forceinline__ float dot4(float4 a, float4 b, float acc) {
    return fmaf(a.x, b.x, fmaf(a.y, b.y, fmaf(a.z, b.z, fmaf(a.w, b.w, acc))));
}

__device__ __forceinline__ float wdot4(const float* __restrict__ wbase, int c, int q,
                                       float4 a, float acc) {
    acc = fmaf(a.x, wbase[(4 * q + 0) * 32 + c], acc);
    acc = fmaf(a.y, wbase[(4 * q + 1) * 32 + c], acc);
    acc = fmaf(a.z, wbase[(4 * q + 2) * 32 + c], acc);
    acc = fmaf(a.w, wbase[(4 * q + 3) * 32 + c], acc);
    return acc;
}

__device__ __forceinline__ float4 sub4(float4 a, float4 b) {
    return make_float4(a.x - b.x, a.y - b.y, a.z - b.z, a.w - b.w);
}

__device__ __forceinline__ unsigned long long key_of(float d2, int idx) {
    unsigned u = __float_as_uint(d2);
    u = (d2 < 0.0f) ? ~u : (u | 0x80000000u);
    return ((unsigned long long)u << 32) | (unsigned)idx;
}

__device__ inline int lower_bound_i(const int* __restrict__ a, int n, int v) {
    int lo = 0, hi = n;
    while (lo < hi) {
        int m = (lo + hi) >> 1;
        if (a[m] < v) lo = m + 1; else hi = m;
    }
    return lo;
}

// one key vs all NS slot keys (macro touches only its param + locals)
#define CMP1(V) { const unsigned long long vv = (V); \
    r0 += (vv < k0); \
    if (NS > 1) r1 += (vv < k1); \
    if (NS > 2) r2 += (vv < k2); \
    if (NS > 3) r3 += (vv < k3); \
    if (NS > 4) r4 += (vv < k4); \
    if (NS > 5) r5 += (vv < k5); }

// Rank counting: chunks of 8 keys via 4 ds_read_b128, double-buffered so the
// next chunk's loads are in flight while the current chunk is compared
// (round-7: unpipelined chunks exposed ~120cyc LDS latency each).
template <int NS>
__device__ __forceinline__ void count_ranks(const unsigned long long* __restrict__ sK, int len,
    unsigned long long k0, unsigned long long k1, unsigned long long k2,
    unsigned long long k3, unsigned long long k4, unsigned long long k5,
    int& r0, int& r1, int& r2, int& r3, int& r4, int& r5)
{
    const ulonglong2* p = reinterpret_cast<const ulonglong2*>(sK);
    const int nch = len >> 3;
    if (nch > 0) {
        ulonglong2 c0 = p[0], c1 = p[1], c2 = p[2], c3 = p[3];
#pragma unroll 1
        for (int ch = 1; ch <= nch; ++ch) {
            ulonglong2 n0, n1, n2, n3;
            if (ch < nch) {
                n0 = p[4 * ch + 0]; n1 = p[4 * ch + 1];
                n2 = p[4 * ch + 2]; n3 = p[4 * ch + 3];
            } else {
                n0.x = n0.y = n1.x = n1.y = 0ull;
                n2.x = n2.y = n3.x = n3.y = 0ull;
            }
            CMP1(c0.x) CMP1(c0.y) CMP1(c1.x) CMP1(c1.y)
            CMP1(c2.x) CMP1(c2.y) CMP1(c3.x) CMP1(c3.y)
            c0 = n0; c1 = n1; c2 = n2; c3 = n3;
        }
    }
#pragma unroll 1
    for (int tt = nch << 3; tt < len; ++tt) CMP1(sK[tt])
}

// ---------------------------------------------------------------------------
// Kernel 1: both MLP2 encoders + sq norms + group-offset tables.
// ---------------------------------------------------------------------------
__launch_bounds__(256)
__global__ void encode_kernel(const float* __restrict__ x_pfc, const float* __restrict__ x_vtx,
                              const int* __restrict__ bpfc, const int* __restrict__ bvtx,
                              const float* __restrict__ pw1, const float* __restrict__ pb1,
                              const float* __restrict__ pw2, const float* __restrict__ pb2,
                              const float* __restrict__ vw1, const float* __restrict__ vb1,
                              const float* __restrict__ vw2, const float* __restrict__ vb2,
                              float* __restrict__ pfc_enc, float* __restrict__ pfc_norm,
                              float* __restrict__ vtx_enc, float* __restrict__ vtx_norm,
                              int* __restrict__ goff_pfc, int* __restrict__ goff_vtx) {
    __shared__ float h1s[8][32];
    const int t = threadIdx.x;
    const int c = t & 31;
    const int nl = t >> 5;

    if (blockIdx.x == 0) {
        if (t < 33) goff_pfc[t] = lower_bound_i(bpfc, 8192, t);
        else if (t >= 64 && t < 97) goff_vtx[t - 64] = lower_bound_i(bvtx, 2048, t - 64);
    }

    const bool is_pfc = (blockIdx.x < 1024);
    const int node = (is_pfc ? blockIdx.x : (blockIdx.x - 1024)) * 8 + nl;
    const int din = is_pfc ? 7 : 4;
    const float* __restrict__ xin = is_pfc ? (x_pfc + node * 7) : (x_vtx + node * 4);
    const float* __restrict__ w1 = is_pfc ? pw1 : vw1;
    const float* __restrict__ b1 = is_pfc ? pb1 : vb1;
    const float* __restrict__ w2 = is_pfc ? pw2 : vw2;
    const float* __restrict__ b2 = is_pfc ? pb2 : vb2;
    float* __restrict__ enc  = is_pfc ? pfc_enc : vtx_enc;
    float* __restrict__ nrm  = is_pfc ? pfc_norm : vtx_norm;

    float h1 = b1[c];
    for (int d = 0; d < din; ++d) h1 = fmaf(xin[d], w1[d * 32 + c], h1);
    h1 = LRELU(h1);
    h1s[nl][c] = h1;
    __syncthreads();

    float h2 = b2[c];
#pragma unroll
    for (int d = 0; d < 32; ++d) h2 = fmaf(h1s[nl][d], w2[d * 32 + c], h2);
    h2 = LRELU(h2);
    enc[node * 32 + c] = h2;

    float s = h2 * h2;
#pragma unroll
    for (int m = 16; m >= 1; m >>= 1) s += __shfl_xor(s, m);
    if (c == 0) nrm[node] = s;
}

// ---------------------------------------------------------------------------
// One wave = one dst node's full edge conv. ALL scratch LDS (sKey, widx,
// sNbr) is wave-private with its OWN storage (no aliasing), so NO block
// barrier appears anywhere in here — same-wave DS ops complete in order;
// __builtin_amdgcn_wave_barrier() (zero-cost) just pins compiler ordering.
// Round-7's 5 block-wide __syncthreads chained the 4 waves to the slowest
// one at every phase (occupancy 11%, VALUBusy 32%).
// ---------------------------------------------------------------------------
__device__ __forceinline__ float edge_conv_wave(
    float4 xi0, float4 xi1, float4 xi2, float4 xi3,
    float4 xi4, float4 xi5, float4 xi6, float4 xi7, float ni,
    const float* __restrict__ srcf, const float* __restrict__ srcn,
    int start, int len, int Ns,
    const float* __restrict__ sW, const float* __restrict__ sB,
    unsigned long long* __restrict__ sKeyW, float4* __restrict__ sNbrW,
    int* __restrict__ widxW, int lane)
{
    const unsigned long long KMAX = ~0ull;

    // Phase 1: distance keys.  d2 = (ni + nj) - 2*dot (ref formula); key is
    // unique (idx in low bits) -> exact ranks incl. top_k tie order.
#pragma unroll 2
    for (int s = lane; s < len; s += 64) {
        const float4* rr = reinterpret_cast<const float4*>(srcf + (size_t)(start + s) * 32);
        float dot = 0.0f;
        dot = dot4(rr[0], xi0, dot); dot = dot4(rr[1], xi1, dot);
        dot = dot4(rr[2], xi2, dot); dot = dot4(rr[3], xi3, dot);
        dot = dot4(rr[4], xi4, dot); dot = dot4(rr[5], xi5, dot);
        dot = dot4(rr[6], xi6, dot); dot = dot4(rr[7], xi7, dot);
        float d2 = (ni + srcn[start + s]) - 2.0f * dot;
        sKeyW[s] = key_of(d2, start + s);
    }
    __builtin_amdgcn_wave_barrier();

    unsigned long long k0 = KMAX, k1 = KMAX, k2 = KMAX, k3 = KMAX, k4 = KMAX, k5 = KMAX;
    if (lane + 0 * 64 < len) k0 = sKeyW[lane + 0 * 64];
    if (lane + 1 * 64 < len) k1 = sKeyW[lane + 1 * 64];
    if (lane + 2 * 64 < len) k2 = sKeyW[lane + 2 * 64];
    if (lane + 3 * 64 < len) k3 = sKeyW[lane + 3 * 64];
    if (lane + 4 * 64 < len) k4 = sKeyW[lane + 4 * 64];
    if (lane + 5 * 64 < len) k5 = sKeyW[lane + 5 * 64];

    int r0 = 0, r1 = 0, r2 = 0, r3 = 0, r4 = 0, r5 = 0;
    const int nsl = (len + 63) >> 6;   // wave-uniform
    if (nsl <= 1)      count_ranks<1>(sKeyW, len, k0, k1, k2, k3, k4, k5, r0, r1, r2, r3, r4, r5);
    else if (nsl == 2) count_ranks<2>(sKeyW, len, k0, k1, k2, k3, k4, k5, r0, r1, r2, r3, r4, r5);
    else if (nsl == 3) count_ranks<3>(sKeyW, len, k0, k1, k2, k3, k4, k5, r0, r1, r2, r3, r4, r5);
    else if (nsl == 4) count_ranks<4>(sKeyW, len, k0, k1, k2, k3, k4, k5, r0, r1, r2, r3, r4, r5);
    else if (nsl == 5) count_ranks<5>(sKeyW, len, k0, k1, k2, k3, k4, k5, r0, r1, r2, r3, r4, r5);
    else               count_ranks<6>(sKeyW, len, k0, k1, k2, k3, k4, k5, r0, r1, r2, r3, r4, r5);

    // Scatter winners (keys unique -> ranks unique)
    if (lane < 16) widxW[lane] = start;  // fallback, len<16 never in practice
    __builtin_amdgcn_wave_barrier();
    if (r0 < 16 && lane + 0 * 64 < len) widxW[r0] = start + lane + 0 * 64;
    if (r1 < 16 && lane + 1 * 64 < len) widxW[r1] = start + lane + 1 * 64;
    if (r2 < 16 && lane + 2 * 64 < len) widxW[r2] = start + lane + 2 * 64;
    if (r3 < 16 && lane + 3 * 64 < len) widxW[r3] = start + lane + 3 * 64;
    if (r4 < 16 && lane + 4 * 64 < len) widxW[r4] = start + lane + 4 * 64;
    if (r5 < 16 && lane + 5 * 64 < len) widxW[r5] = start + lane + 5 * 64;
    __builtin_amdgcn_wave_barrier();

    // Stage 16 neighbor rows (128 float4, 2 independent global loads/lane);
    // compute `base` while the loads are in flight.
    const int n0 = lane >> 3, q0 = lane & 7;
    const int n1 = n0 + 8;
    int j0 = widxW[n0]; j0 = ((unsigned)j0 < (unsigned)Ns) ? j0 : 0;
    int j1 = widxW[n1]; j1 = ((unsigned)j1 < (unsigned)Ns) ? j1 : 0;
    float4 v0 = reinterpret_cast<const float4*>(srcf + (size_t)j0 * 32)[q0];
    float4 v1 = reinterpret_cast<const float4*>(srcf + (size_t)j1 * 32)[q0];

    const int c = lane & 31;
    float base = sB[c];
    base = wdot4(sW, c, 0, xi0, base); base = wdot4(sW, c, 1, xi1, base);
    base = wdot4(sW, c, 2, xi2, base); base = wdot4(sW, c, 3, xi3, base);
    base = wdot4(sW, c, 4, xi4, base); base = wdot4(sW, c, 5, xi5, base);
    base = wdot4(sW, c, 6, xi6, base); base = wdot4(sW, c, 7, xi7, base);

    sNbrW[n0 * 8 + q0] = v0;
    sNbrW[n1 * 8 + q0] = v1;
    __builtin_amdgcn_wave_barrier();

    // Conv: two neighbors per round (half-wave each)
    const int half = lane >> 5;
    const float* sW2nd = sW + 1024;   // rows 32..63 (the x_j - x_i part)
    float vmax = -__builtin_huge_valf();
#pragma unroll 1
    for (int r = 0; r < 8; ++r) {
        const float4* nb = sNbrW + (2 * r + half) * 8;
        float acc = base;
        acc = wdot4(sW2nd, c, 0, sub4(nb[0], xi0), acc);
        acc = wdot4(sW2nd, c, 1, sub4(nb[1], xi1), acc);
        acc = wdot4(sW2nd, c, 2, sub4(nb[2], xi2), acc);
        acc = wdot4(sW2nd, c, 3, sub4(nb[3], xi3), acc);
        acc = wdot4(sW2nd, c, 4, sub4(nb[4], xi4), acc);
        acc = wdot4(sW2nd, c, 5, sub4(nb[5], xi5), acc);
        acc = wdot4(sW2nd, c, 6, sub4(nb[6], xi6), acc);
        acc = wdot4(sW2nd, c, 7, sub4(nb[7], xi7), acc);
        vmax = fmaxf(vmax, LRELU(acc));
    }
    vmax = fmaxf(vmax, __shfl_xor(vmax, 32));
    return vmax;   // every lane holds channel (lane&31)'s value
}

// ---------------------------------------------------------------------------
// Kernel 2: FUSED conv1 + conv2 + output MLP. Everything after encode is
// node-local, so one wave carries node i end-to-end with zero block barriers
// after the conv-weight staging. MLP weights are read straight from global
// (every wave reads the same 16KB -> L2-hot broadcast).
// ---------------------------------------------------------------------------
__launch_bounds__(256)
__global__ void fused_conv_mlp_kernel(
    const float* __restrict__ pfc_enc, const float* __restrict__ n_pfc,
    const float* __restrict__ vtx_enc, const float* __restrict__ n_vtx,
    const int* __restrict__ bpfc,
    const int* __restrict__ goff_pfc, const int* __restrict__ goff_vtx,
    const float* __restrict__ W, const float* __restrict__ Bc,
    const float* __restrict__ ow1, const float* __restrict__ ob1,
    const float* __restrict__ ow2, const float* __restrict__ ob2,
    const float* __restrict__ ow3, const float* __restrict__ ob3,
    const float* __restrict__ ow4, const float* __restrict__ ob4,
    float* __restrict__ dout, int N)
{
    __shared__ float sW[2048];
    __shared__ float sB[32];
    __shared__ __align__(16) unsigned long long sKey[4][384];
    __shared__ __align__(16) float4 sNbr[4][128];
    __shared__ int widx[4][16];
    __shared__ __align__(16) float sRow[4][32];
    __shared__ float sEx1[4][64];

    const int t = threadIdx.x;
    const int lane = t & 63;
    const int w = t >> 6;
    const int i = blockIdx.x * 4 + w;    // grid covers 8192 exactly

    for (int k = t; k < 2048; k += 256) sW[k] = W[k];
    if (t < 32) sB[t] = Bc[t];
    __syncthreads();   // the ONLY block barrier

    unsigned long long* sKeyW = &sKey[w][0];
    float4* sNbrW = &sNbr[w][0];
    int* widxW = &widx[w][0];

    const int g = bpfc[i];

    // ---- conv1: src = dst = pfc_enc (group ~256±16) ----
    const float4* xr = reinterpret_cast<const float4*>(pfc_enc + (size_t)i * 32);
    const float4 xi0 = xr[0], xi1 = xr[1], xi2 = xr[2], xi3 = xr[3],
                 xi4 = xr[4], xi5 = xr[5], xi6 = xr[6], xi7 = xr[7];
    const int s1 = goff_pfc[g];
    const int len1 = min(goff_pfc[g + 1] - s1, 384);
    float v1 = edge_conv_wave(xi0, xi1, xi2, xi3, xi4, xi5, xi6, xi7, n_pfc[i],
                              pfc_enc, n_pfc, s1, len1, 8192,
                              sW, sB, sKeyW, sNbrW, widxW, lane);

    if (lane < 32) sRow[w][lane] = v1;
    float nf1 = v1 * v1;
#pragma unroll
    for (int m = 16; m >= 1; m >>= 1) nf1 += __shfl_xor(nf1, m);  // |feats1_i|^2
    __builtin_amdgcn_wave_barrier();

    // ---- conv2: dst = feats1 row (per-wave LDS), src = vtx_enc (~64±8) ----
    const float4* fr = reinterpret_cast<const float4*>(&sRow[w][0]);
    const float4 y0 = fr[0], y1 = fr[1], y2 = fr[2], y3 = fr[3],
                 y4 = fr[4], y5 = fr[5], y6 = fr[6], y7 = fr[7];
    const int s2 = goff_vtx[g];
    const int len2 = min(goff_vtx[g + 1] - s2, 384);
    float v2 = edge_conv_wave(y0, y1, y2, y3, y4, y5, y6, y7, nf1,
                              vtx_enc, n_vtx, s2, len2, 2048,
                              sW, sB, sKeyW, sNbrW, widxW, lane);

    // ---- output MLP 32 -> 64 -> 32 -> 4 -> 1 (lrelu each) ----
    if (lane < 32) sRow[w][lane] = v2;
    __builtin_amdgcn_wave_barrier();

    float h1 = ob1[lane];
#pragma unroll 8
    for (int d = 0; d < 32; ++d) h1 = fmaf(sRow[w][d], ow1[d * 64 + lane], h1);
    h1 = LRELU(h1);
    sEx1[w][lane] = h1;
    __builtin_amdgcn_wave_barrier();

    const int c = lane & 31;
    float h2 = ob2[c];
#pragma unroll 8
    for (int d = 0; d < 64; ++d) h2 = fmaf(sEx1[w][d], ow2[d * 32 + c], h2);
    h2 = LRELU(h2);
    if (lane < 32) sRow[w][lane] = h2;
    __builtin_amdgcn_wave_barrier();

    float a0 = ob3[0], a1 = ob3[1], a2 = ob3[2], a3 = ob3[3];
#pragma unroll 8
    for (int d = 0; d < 32; ++d) {
        float e = sRow[w][d];
        a0 = fmaf(e, ow3[d * 4 + 0], a0);
        a1 = fmaf(e, ow3[d * 4 + 1], a1);
        a2 = fmaf(e, ow3[d * 4 + 2], a2);
        a3 = fmaf(e, ow3[d * 4 + 3], a3);
    }
    a0 = LRELU(a0); a1 = LRELU(a1); a2 = LRELU(a2); a3 = LRELU(a3);
    float o = ob4[0];
    o = fmaf(a0, ow4[0], o); o = fmaf(a1, ow4[1], o);
    o = fmaf(a2, ow4[2], o); o = fmaf(a3, ow4[3], o);
    o = LRELU(o);

    if (lane == 0) dout[i] = o;                   // output 0: (8192,1)
    if (lane == 1) dout[N + i] = (float)g;        // output 1: batch_pfc
}

// ---------------------------------------------------------------------------
extern "C" void kernel_launch(void* const* d_in, const int* in_sizes, int n_in,
                              void* d_out, int out_size, void* d_ws, size_t ws_size,
                              hipStream_t stream) {
    const float* x_pfc     = (const float*)d_in[0];
    const float* x_vtx     = (const float*)d_in[1];
    const int*   batch_pfc = (const int*)d_in[2];
    const int*   batch_vtx = (const int*)d_in[3];
    const float* pfc_w1 = (const float*)d_in[4];
    const float* pfc_b1 = (const float*)d_in[5];
    const float* pfc_w2 = (const float*)d_in[6];
    const float* pfc_b2 = (const float*)d_in[7];
    const float* vtx_w1 = (const float*)d_in[8];
    const float* vtx_b1 = (const float*)d_in[9];
    const float* vtx_w2 = (const float*)d_in[10];
    const float* vtx_b2 = (const float*)d_in[11];
    const float* conv_w = (const float*)d_in[12];
    const float* conv_b = (const float*)d_in[13];
    const float* out_w1 = (const float*)d_in[14];
    const float* out_b1 = (const float*)d_in[15];
    const float* out_w2 = (const float*)d_in[16];
    const float* out_b2 = (const float*)d_in[17];
    const float* out_w3 = (const float*)d_in[18];
    const float* out_b3 = (const float*)d_in[19];
    const float* out_w4 = (const float*)d_in[20];
    const float* out_b4 = (const float*)d_in[21];

    const int N_PFC = 8192;

    float* ws = (float*)d_ws;
    float* pfc_enc = ws;                     // 8192*32
    float* vtx_enc = ws + 262144;            // 2048*32
    float* n_pfc   = ws + 327680;            // 8192
    float* n_vtx   = ws + 335872;            // 2048
    int*   goff_pfc = (int*)(ws + 337920);   // 33
    int*   goff_vtx = (int*)(ws + 337984);   // 33

    encode_kernel<<<1280, 256, 0, stream>>>(x_pfc, x_vtx, batch_pfc, batch_vtx,
                                            pfc_w1, pfc_b1, pfc_w2, pfc_b2,
                                            vtx_w1, vtx_b1, vtx_w2, vtx_b2,
                                            pfc_enc, n_pfc, vtx_enc, n_vtx,
                                            goff_pfc, goff_vtx);

    fused_conv_mlp_kernel<<<2048, 256, 0, stream>>>(
        pfc_enc, n_pfc, vtx_enc, n_vtx, batch_pfc, goff_pfc, goff_vtx,
        conv_w, conv_b,
        out_w1, out_b1, out_w2, out_b2, out_w3, out_b3, out_w4, out_b4,
        (float*)d_out, N_PFC);
}

// Round 9
// 204.747 us; speedup vs baseline: 1.6004x; 1.6004x over previous
//
#include <hip/hip_runtime.h>
#include <hip/hip_bf16.h>

#define LRELU(val) ((val) >= 0.0f ? (val) : 0.01f * (val))

__device__ __forceinline__ float dot4(float4 a, float4 b, float acc) {
    return fmaf(a.x, b.x, fmaf(a.y, b.y, fmaf(a.z, b.z, fmaf(a.w, b.w, acc))));
}

// acc += quad `a` dotted with rows (4q..4q+3), column c, of a 32-col row-major slab
__device__ __forceinline__ float wdot4(const float* __restrict__ wbase, int c, int q,
                                       float4 a, float acc) {
    acc = fmaf(a.x, wbase[(4 * q + 0) * 32 + c], acc);
    acc = fmaf(a.y, wbase[(4 * q + 1) * 32 + c], acc);
    acc = fmaf(a.z, wbase[(4 * q + 2) * 32 + c], acc);
    acc = fmaf(a.w, wbase[(4 * q + 3) * 32 + c], acc);
    return acc;
}

__device__ inline int lower_bound_i(const int* __restrict__ a, int n, int v) {
    int lo = 0, hi = n;
    while (lo < hi) {
        int m = (lo + hi) >> 1;
        if (a[m] < v) lo = m + 1; else hi = m;
    }
    return lo;
}

// Sortable 32-bit distance key for candidate slot s (named-register resident).
__device__ __forceinline__ unsigned slot_key(
    int s, int lane, int start, int len, int Ns,
    const float* __restrict__ srcf, const float* __restrict__ srcn, float ni,
    float4 xi0, float4 xi1, float4 xi2, float4 xi3,
    float4 xi4, float4 xi5, float4 xi6, float4 xi7)
{
    const int o = lane + 64 * s;
    const bool valid = o < len;
    const int j = valid ? (start + o) : min(start, Ns - 1);
    const float4* rr = reinterpret_cast<const float4*>(srcf + (size_t)j * 32);
    float dot = 0.0f;
    dot = dot4(rr[0], xi0, dot); dot = dot4(rr[1], xi1, dot);
    dot = dot4(rr[2], xi2, dot); dot = dot4(rr[3], xi3, dot);
    dot = dot4(rr[4], xi4, dot); dot = dot4(rr[5], xi5, dot);
    dot = dot4(rr[6], xi6, dot); dot = dot4(rr[7], xi7, dot);
    float d2 = (ni + srcn[j]) - 2.0f * dot;   // reference distance formula
    unsigned u = __float_as_uint(d2);
    u = (d2 < 0.0f) ? ~u : (u | 0x80000000u); // monotone float->uint map
    return valid ? u : 0xFFFFFFFFu;           // invalid slots never selected
}

// ---------------------------------------------------------------------------
// Kernel 1: both MLP2 encoders + sq norms + group-offset tables.
// ---------------------------------------------------------------------------
__launch_bounds__(256)
__global__ void encode_kernel(const float* __restrict__ x_pfc, const float* __restrict__ x_vtx,
                              const int* __restrict__ bpfc, const int* __restrict__ bvtx,
                              const float* __restrict__ pw1, const float* __restrict__ pb1,
                              const float* __restrict__ pw2, const float* __restrict__ pb2,
                              const float* __restrict__ vw1, const float* __restrict__ vb1,
                              const float* __restrict__ vw2, const float* __restrict__ vb2,
                              float* __restrict__ pfc_enc, float* __restrict__ pfc_norm,
                              float* __restrict__ vtx_enc, float* __restrict__ vtx_norm,
                              int* __restrict__ goff_pfc, int* __restrict__ goff_vtx) {
    __shared__ float h1s[8][32];
    const int t = threadIdx.x;
    const int c = t & 31;
    const int nl = t >> 5;

    if (blockIdx.x == 0) {
        if (t < 33) goff_pfc[t] = lower_bound_i(bpfc, 8192, t);
        else if (t >= 64 && t < 97) goff_vtx[t - 64] = lower_bound_i(bvtx, 2048, t - 64);
    }

    const bool is_pfc = (blockIdx.x < 1024);
    const int node = (is_pfc ? blockIdx.x : (blockIdx.x - 1024)) * 8 + nl;
    const int din = is_pfc ? 7 : 4;
    const float* __restrict__ xin = is_pfc ? (x_pfc + node * 7) : (x_vtx + node * 4);
    const float* __restrict__ w1 = is_pfc ? pw1 : vw1;
    const float* __restrict__ b1 = is_pfc ? pb1 : vb1;
    const float* __restrict__ w2 = is_pfc ? pw2 : vw2;
    const float* __restrict__ b2 = is_pfc ? pb2 : vb2;
    float* __restrict__ enc  = is_pfc ? pfc_enc : vtx_enc;
    float* __restrict__ nrm  = is_pfc ? pfc_norm : vtx_norm;

    float h1 = b1[c];
    for (int d = 0; d < din; ++d) h1 = fmaf(xin[d], w1[d * 32 + c], h1);
    h1 = LRELU(h1);
    h1s[nl][c] = h1;
    __syncthreads();

    float h2 = b2[c];
#pragma unroll
    for (int d = 0; d < 32; ++d) h2 = fmaf(h1s[nl][d], w2[d * 32 + c], h2);
    h2 = LRELU(h2);
    enc[node * 32 + c] = h2;

    float s = h2 * h2;
#pragma unroll
    for (int m = 16; m >= 1; m >>= 1) s += __shfl_xor(s, m);
    if (c == 0) nrm[node] = s;
}

// ---------------------------------------------------------------------------
// One wave = one dst node's edge conv. Selection = ballot BISECTION:
// keys live in <=6 named VGPRs/lane (NO key LDS, no count loop). 32-step
// scalar bisection finds T = exact 16th-smallest key; membership = k<T plus
// idx-ordered prefix among k==T (exact lax.top_k tie semantics); compaction
// to widx via ballot prefix counts. Conv weights W2 live in 8 float4 VGPRs
// (no per-fma ds_read_b32 — round-8's LDS-pipe saturation). No block
// barriers anywhere; all scratch LDS is wave-private.
// ---------------------------------------------------------------------------
__device__ __forceinline__ float edge_conv_wave(
    float4 xi0, float4 xi1, float4 xi2, float4 xi3,
    float4 xi4, float4 xi5, float4 xi6, float4 xi7, float ni,
    const float* __restrict__ srcf, const float* __restrict__ srcn,
    int start, int len, int Ns,
    const float* __restrict__ W, const float* __restrict__ Bc,
    float4 w2_0, float4 w2_1, float4 w2_2, float4 w2_3,
    float4 w2_4, float4 w2_5, float4 w2_6, float4 w2_7,
    float4* __restrict__ sNbrW, int* __restrict__ widxW, int lane)
{
    // Phase 1: distance keys (named regs; slots uniformly skipped past len)
    unsigned k0 = 0xFFFFFFFFu, k1 = 0xFFFFFFFFu, k2 = 0xFFFFFFFFu,
             k3 = 0xFFFFFFFFu, k4 = 0xFFFFFFFFu, k5 = 0xFFFFFFFFu;
    if (len > 0)   k0 = slot_key(0, lane, start, len, Ns, srcf, srcn, ni, xi0, xi1, xi2, xi3, xi4, xi5, xi6, xi7);
    if (len > 64)  k1 = slot_key(1, lane, start, len, Ns, srcf, srcn, ni, xi0, xi1, xi2, xi3, xi4, xi5, xi6, xi7);
    if (len > 128) k2 = slot_key(2, lane, start, len, Ns, srcf, srcn, ni, xi0, xi1, xi2, xi3, xi4, xi5, xi6, xi7);
    if (len > 192) k3 = slot_key(3, lane, start, len, Ns, srcf, srcn, ni, xi0, xi1, xi2, xi3, xi4, xi5, xi6, xi7);
    if (len > 256) k4 = slot_key(4, lane, start, len, Ns, srcf, srcn, ni, xi0, xi1, xi2, xi3, xi4, xi5, xi6, xi7);
    if (len > 320) k5 = slot_key(5, lane, start, len, Ns, srcf, srcn, ni, xi0, xi1, xi2, xi3, xi4, xi5, xi6, xi7);

    // Phase 2: bisect for T = exact 16th smallest key (scalar state).
    unsigned lo = 0u, hi = 0xFFFFFFFFu;
#pragma unroll 1
    for (int it = 0; it < 32; ++it) {
        unsigned mid = lo + ((hi - lo) >> 1);
        int cnt = __popcll(__ballot(k0 <= mid)) + __popcll(__ballot(k1 <= mid))
                + __popcll(__ballot(k2 <= mid)) + __popcll(__ballot(k3 <= mid))
                + __popcll(__ballot(k4 <= mid)) + __popcll(__ballot(k5 <= mid));
        if (cnt >= 16) hi = mid; else lo = mid + 1;
        if (lo == hi) break;
    }
    const unsigned T = lo;

    // Phase 3: membership + compaction.  m = #{k<T} <= 15; take (16-m) of the
    // ==T keys in ascending idx order (idx = start + lane + 64*s, s-major).
    const int m = __popcll(__ballot(k0 < T)) + __popcll(__ballot(k1 < T))
                + __popcll(__ballot(k2 < T)) + __popcll(__ballot(k3 < T))
                + __popcll(__ballot(k4 < T)) + __popcll(__ballot(k5 < T));
    const int need = 16 - m;
    const unsigned long long e0 = __ballot(k0 == T), e1 = __ballot(k1 == T),
                             e2 = __ballot(k2 == T), e3 = __ballot(k3 == T),
                             e4 = __ballot(k4 == T), e5 = __ballot(k5 == T);
    const unsigned long long below = (1ull << lane) - 1ull;
    const int eq0 = __popcll(e0), eq1 = eq0 + __popcll(e1), eq2 = eq1 + __popcll(e2),
              eq3 = eq2 + __popcll(e3), eq4 = eq3 + __popcll(e4);
    const bool sel0 = (k0 < T) || ((k0 == T) && (__popcll(e0 & below) < need));
    const bool sel1 = (k1 < T) || ((k1 == T) && (eq0 + __popcll(e1 & below) < need));
    const bool sel2 = (k2 < T) || ((k2 == T) && (eq1 + __popcll(e2 & below) < need));
    const bool sel3 = (k3 < T) || ((k3 == T) && (eq2 + __popcll(e3 & below) < need));
    const bool sel4 = (k4 < T) || ((k4 == T) && (eq3 + __popcll(e4 & below) < need));
    const bool sel5 = (k5 < T) || ((k5 == T) && (eq4 + __popcll(e5 & below) < need));
    const unsigned long long s0 = __ballot(sel0), s1 = __ballot(sel1), s2 = __ballot(sel2),
                             s3 = __ballot(sel3), s4 = __ballot(sel4), s5 = __ballot(sel5);
    const int c0 = __popcll(s0), c1 = c0 + __popcll(s1), c2 = c1 + __popcll(s2),
              c3 = c2 + __popcll(s3), c4 = c3 + __popcll(s4);
    (void)s5;
    if (lane < 16) widxW[lane] = min(start, Ns - 1);   // fallback, len<16 never in practice
    __builtin_amdgcn_wave_barrier();
    if (sel0) widxW[__popcll(s0 & below)] = start + lane;
    if (sel1) widxW[c0 + __popcll(s1 & below)] = start + lane + 64;
    if (sel2) widxW[c1 + __popcll(s2 & below)] = start + lane + 128;
    if (sel3) widxW[c2 + __popcll(s3 & below)] = start + lane + 192;
    if (sel4) widxW[c3 + __popcll(s4 & below)] = start + lane + 256;
    if (sel5) widxW[c4 + __popcll(s5 & below)] = start + lane + 320;
    __builtin_amdgcn_wave_barrier();

    // Stage 16 neighbor rows to wave-private LDS (2 independent loads/lane),
    // computing cbase = Bc + xi*W1 - xi*W2 while the loads are in flight.
    const int n0 = lane >> 3, qq = lane & 7;
    const int n1 = n0 + 8;
    int j0 = widxW[n0]; j0 = ((unsigned)j0 < (unsigned)Ns) ? j0 : 0;
    int j1 = widxW[n1]; j1 = ((unsigned)j1 < (unsigned)Ns) ? j1 : 0;
    const float4 v0 = reinterpret_cast<const float4*>(srcf + (size_t)j0 * 32)[qq];
    const float4 v1 = reinterpret_cast<const float4*>(srcf + (size_t)j1 * 32)[qq];

    const int c = lane & 31;
    float base = Bc[c];                           // W rows 0..31 straight from global (L2-hot)
    base = wdot4(W, c, 0, xi0, base); base = wdot4(W, c, 1, xi1, base);
    base = wdot4(W, c, 2, xi2, base); base = wdot4(W, c, 3, xi3, base);
    base = wdot4(W, c, 4, xi4, base); base = wdot4(W, c, 5, xi5, base);
    base = wdot4(W, c, 6, xi6, base); base = wdot4(W, c, 7, xi7, base);
    float bx2 = 0.0f;                             // xi · W2 (register-resident weights)
    bx2 = dot4(xi0, w2_0, bx2); bx2 = dot4(xi1, w2_1, bx2);
    bx2 = dot4(xi2, w2_2, bx2); bx2 = dot4(xi3, w2_3, bx2);
    bx2 = dot4(xi4, w2_4, bx2); bx2 = dot4(xi5, w2_5, bx2);
    bx2 = dot4(xi6, w2_6, bx2); bx2 = dot4(xi7, w2_7, bx2);
    const float cbase = base - bx2;               // h = cbase + nb·W2

    sNbrW[n0 * 8 + qq] = v0;
    sNbrW[n1 * 8 + qq] = v1;
    __builtin_amdgcn_wave_barrier();

    // Conv: two neighbors per round (half-wave each); 32 reg-fma per neighbor.
    const int half = lane >> 5;
    float vmax = -__builtin_huge_valf();
#pragma unroll 1
    for (int r = 0; r < 8; ++r) {
        const float4* nb = sNbrW + (2 * r + half) * 8;
        float acc = cbase;
        acc = dot4(nb[0], w2_0, acc); acc = dot4(nb[1], w2_1, acc);
        acc = dot4(nb[2], w2_2, acc); acc = dot4(nb[3], w2_3, acc);
        acc = dot4(nb[4], w2_4, acc); acc = dot4(nb[5], w2_5, acc);
        acc = dot4(nb[6], w2_6, acc); acc = dot4(nb[7], w2_7, acc);
        vmax = fmaxf(vmax, LRELU(acc));
    }
    vmax = fmaxf(vmax, __shfl_xor(vmax, 32));
    return vmax;   // every lane holds channel (lane&31)'s value
}

// ---------------------------------------------------------------------------
// Kernel 2: fused conv1 + conv2, one wave per node, ZERO block barriers.
// ---------------------------------------------------------------------------
__launch_bounds__(256)
__global__ void fused_conv_kernel(
    const float* __restrict__ pfc_enc, const float* __restrict__ n_pfc,
    const float* __restrict__ vtx_enc, const float* __restrict__ n_vtx,
    const int* __restrict__ bpfc,
    const int* __restrict__ goff_pfc, const int* __restrict__ goff_vtx,
    const float* __restrict__ W, const float* __restrict__ Bc,
    float* __restrict__ feats2)
{
    __shared__ __align__(16) float4 sNbr[4][128];
    __shared__ int widx[4][16];
    __shared__ __align__(16) float sRow[4][32];

    const int t = threadIdx.x;
    const int lane = t & 63;
    const int w = t >> 6;
    const int i = blockIdx.x * 4 + w;   // grid covers 8192 exactly
    const int c = lane & 31;
    const int g = bpfc[i];

    // W2 column (rows 32..63, col c) into 8 float4 regs — one-time L2 broadcast
    const float4 w2_0 = make_float4(W[32 * 32 + c], W[33 * 32 + c], W[34 * 32 + c], W[35 * 32 + c]);
    const float4 w2_1 = make_float4(W[36 * 32 + c], W[37 * 32 + c], W[38 * 32 + c], W[39 * 32 + c]);
    const float4 w2_2 = make_float4(W[40 * 32 + c], W[41 * 32 + c], W[42 * 32 + c], W[43 * 32 + c]);
    const float4 w2_3 = make_float4(W[44 * 32 + c], W[45 * 32 + c], W[46 * 32 + c], W[47 * 32 + c]);
    const float4 w2_4 = make_float4(W[48 * 32 + c], W[49 * 32 + c], W[50 * 32 + c], W[51 * 32 + c]);
    const float4 w2_5 = make_float4(W[52 * 32 + c], W[53 * 32 + c], W[54 * 32 + c], W[55 * 32 + c]);
    const float4 w2_6 = make_float4(W[56 * 32 + c], W[57 * 32 + c], W[58 * 32 + c], W[59 * 32 + c]);
    const float4 w2_7 = make_float4(W[60 * 32 + c], W[61 * 32 + c], W[62 * 32 + c], W[63 * 32 + c]);

    float4* sNbrW = &sNbr[w][0];
    int* widxW = &widx[w][0];

    // ---- conv1: src = dst = pfc_enc (group ~256±16) ----
    const float4* xr = reinterpret_cast<const float4*>(pfc_enc + (size_t)i * 32);
    const float4 xi0 = xr[0], xi1 = xr[1], xi2 = xr[2], xi3 = xr[3],
                 xi4 = xr[4], xi5 = xr[5], xi6 = xr[6], xi7 = xr[7];
    const int s1 = goff_pfc[g];
    const int len1 = min(goff_pfc[g + 1] - s1, 384);
    float v1 = edge_conv_wave(xi0, xi1, xi2, xi3, xi4, xi5, xi6, xi7, n_pfc[i],
                              pfc_enc, n_pfc, s1, len1, 8192, W, Bc,
                              w2_0, w2_1, w2_2, w2_3, w2_4, w2_5, w2_6, w2_7,
                              sNbrW, widxW, lane);

    if (lane < 32) sRow[w][lane] = v1;
    float nf1 = v1 * v1;
#pragma unroll
    for (int m = 16; m >= 1; m >>= 1) nf1 += __shfl_xor(nf1, m);  // |feats1_i|^2 (per half)
    __builtin_amdgcn_wave_barrier();

    // ---- conv2: dst = feats1 row (wave-private LDS), src = vtx_enc (~64±8) ----
    const float4* fr = reinterpret_cast<const float4*>(&sRow[w][0]);
    const float4 y0 = fr[0], y1 = fr[1], y2 = fr[2], y3 = fr[3],
                 y4 = fr[4], y5 = fr[5], y6 = fr[6], y7 = fr[7];
    const int s2 = goff_vtx[g];
    const int len2 = min(goff_vtx[g + 1] - s2, 384);
    float v2 = edge_conv_wave(y0, y1, y2, y3, y4, y5, y6, y7, nf1,
                              vtx_enc, n_vtx, s2, len2, 2048, W, Bc,
                              w2_0, w2_1, w2_2, w2_3, w2_4, w2_5, w2_6, w2_7,
                              sNbrW, widxW, lane);

    if (lane < 32) feats2[(size_t)i * 32 + lane] = v2;
}

// ---------------------------------------------------------------------------
// Kernel 3: output MLP 32 -> 64 -> 32 -> 4 -> 1 (lrelu each) + batch copy.
// (R6 version — LDS-staged weights; measured cheap.)
// ---------------------------------------------------------------------------
__launch_bounds__(256)
__global__ void out_mlp_kernel(const float* __restrict__ f2, const int* __restrict__ bpfc,
                               const float* __restrict__ w1, const float* __restrict__ b1,
                               const float* __restrict__ w2, const float* __restrict__ b2,
                               const float* __restrict__ w3, const float* __restrict__ b3,
                               const float* __restrict__ w4, const float* __restrict__ b4,
                               float* __restrict__ dout, int N) {
    __shared__ float sW1[32 * 64], sW2[64 * 32], sW3[32 * 4];
    __shared__ float sB1[64], sB2[32], sB3[4], sW4[4], sB4[1];
    __shared__ float ex1[4][64];
    __shared__ float ex2[4][32];

    const int t = threadIdx.x;
    for (int k = t; k < 2048; k += 256) { sW1[k] = w1[k]; sW2[k] = w2[k]; }
    if (t < 128) sW3[t] = w3[t];
    if (t < 64)  sB1[t] = b1[t];
    if (t < 32)  sB2[t] = b2[t];
    if (t < 4)   { sB3[t] = b3[t]; sW4[t] = w4[t]; }
    if (t == 0)  sB4[0] = b4[0];
    __syncthreads();

    const int w = t >> 6;
    const int lane = t & 63;
    const int i = blockIdx.x * 4 + w;

    const float* fr = f2 + (size_t)i * 32;

    float h1 = sB1[lane];
#pragma unroll
    for (int d = 0; d < 32; ++d) h1 = fmaf(fr[d], sW1[d * 64 + lane], h1);
    h1 = LRELU(h1);
    ex1[w][lane] = h1;
    __syncthreads();

    const int c = lane & 31;
    float h2 = sB2[c];
#pragma unroll
    for (int d = 0; d < 64; ++d) h2 = fmaf(ex1[w][d], sW2[d * 32 + c], h2);
    h2 = LRELU(h2);
    if (lane < 32) ex2[w][c] = h2;
    __syncthreads();

    float a0 = sB3[0], a1 = sB3[1], a2 = sB3[2], a3 = sB3[3];
#pragma unroll
    for (int d = 0; d < 32; ++d) {
        float e = ex2[w][d];
        a0 = fmaf(e, sW3[d * 4 + 0], a0);
        a1 = fmaf(e, sW3[d * 4 + 1], a1);
        a2 = fmaf(e, sW3[d * 4 + 2], a2);
        a3 = fmaf(e, sW3[d * 4 + 3], a3);
    }
    a0 = LRELU(a0); a1 = LRELU(a1); a2 = LRELU(a2); a3 = LRELU(a3);
    float o = sB4[0];
    o = fmaf(a0, sW4[0], o); o = fmaf(a1, sW4[1], o);
    o = fmaf(a2, sW4[2], o); o = fmaf(a3, sW4[3], o);
    o = LRELU(o);

    if (lane == 0) dout[i] = o;                       // output 0: (8192,1)
    if (lane == 1) dout[N + i] = (float)bpfc[i];      // output 1: batch_pfc
}

// ---------------------------------------------------------------------------
extern "C" void kernel_launch(void* const* d_in, const int* in_sizes, int n_in,
                              void* d_out, int out_size, void* d_ws, size_t ws_size,
                              hipStream_t stream) {
    const float* x_pfc     = (const float*)d_in[0];
    const float* x_vtx     = (const float*)d_in[1];
    const int*   batch_pfc = (const int*)d_in[2];
    const int*   batch_vtx = (const int*)d_in[3];
    const float* pfc_w1 = (const float*)d_in[4];
    const float* pfc_b1 = (const float*)d_in[5];
    const float* pfc_w2 = (const float*)d_in[6];
    const float* pfc_b2 = (const float*)d_in[7];
    const float* vtx_w1 = (const float*)d_in[8];
    const float* vtx_b1 = (const float*)d_in[9];
    const float* vtx_w2 = (const float*)d_in[10];
    const float* vtx_b2 = (const float*)d_in[11];
    const float* conv_w = (const float*)d_in[12];
    const float* conv_b = (const float*)d_in[13];
    const float* out_w1 = (const float*)d_in[14];
    const float* out_b1 = (const float*)d_in[15];
    const float* out_w2 = (const float*)d_in[16];
    const float* out_b2 = (const float*)d_in[17];
    const float* out_w3 = (const float*)d_in[18];
    const float* out_b3 = (const float*)d_in[19];
    const float* out_w4 = (const float*)d_in[20];
    const float* out_b4 = (const float*)d_in[21];

    const int N_PFC = 8192;

    float* ws = (float*)d_ws;
    float* pfc_enc = ws;                     // 8192*32
    float* vtx_enc = ws + 262144;            // 2048*32
    float* feats2  = ws + 327680;            // 8192*32
    float* n_pfc   = ws + 589824;            // 8192
    float* n_vtx   = ws + 598016;            // 2048
    int*   goff_pfc = (int*)(ws + 600064);   // 33
    int*   goff_vtx = (int*)(ws + 600128);   // 33

    encode_kernel<<<1280, 256, 0, stream>>>(x_pfc, x_vtx, batch_pfc, batch_vtx,
                                            pfc_w1, pfc_b1, pfc_w2, pfc_b2,
                                            vtx_w1, vtx_b1, vtx_w2, vtx_b2,
                                            pfc_enc, n_pfc, vtx_enc, n_vtx,
                                            goff_pfc, goff_vtx);

    fused_conv_kernel<<<2048, 256, 0, stream>>>(pfc_enc, n_pfc, vtx_enc, n_vtx,
                                                batch_pfc, goff_pfc, goff_vtx,
                                                conv_w, conv_b, feats2);

    out_mlp_kernel<<<2048, 256, 0, stream>>>(feats2, batch_pfc,
                                             out_w1, out_b1, out_w2, out_b2,
                                             out_w3, out_b3, out_w4, out_b4,
                                             (float*)d_out, N_PFC);
}